// Round 15
// baseline (251.347 us; speedup 1.0000x reference)
//
#include <hip/hip_runtime.h>
#include <hip/hip_bf16.h>

typedef __bf16 bf16_t;
typedef __bf16 bf16x8 __attribute__((ext_vector_type(8)));
typedef __bf16 bf16x4 __attribute__((ext_vector_type(4)));
typedef __bf16 bf16x2 __attribute__((ext_vector_type(2)));
typedef float  f32x4  __attribute__((ext_vector_type(4)));

struct OutDesc { bf16_t* ptr; const float* bias; int stride; };
struct Descs { OutDesc d[6]; };

__device__ __forceinline__ float sigm(float v) { return 1.f / (1.f + __expf(-v)); }

// ---------------- weight prep ----------------
__global__ void prep_wx(const float* __restrict__ W1, const float* __restrict__ Wg,
                        const float* __restrict__ Whh, bf16_t* __restrict__ WxT,
                        int* __restrict__ degi, int N)
{
    int t = blockIdx.x * 256 + threadIdx.x;   // 768*128 = 98304 threads
    if (t < N) degi[t] = 0;
    int c = t >> 7, k = t & 127;
    float v;
    if (c < 128)      v = W1[k * 128 + c];                                   // XA: x[dst] part
    else if (c < 256) v = W1[(128 + k) * 128 + (c - 128)];                   // XB: x[src] part
    else if (c < 384) { int cc = c - 256; v = Wg[k * 128 + cc] + Wg[(256 + k) * 128 + cc]; } // GX
    else              { int j = c - 384; v = Whh[j * 128 + k]; }             // GH: W_hh^T
    WxT[t] = (bf16_t)v;
}

__global__ void prep_wh(const float* __restrict__ W2, const float* __restrict__ Wg,
                        const float* __restrict__ Wih, const float* __restrict__ b2,
                        bf16_t* __restrict__ WhT, float* __restrict__ db)
{
    int t = blockIdx.x * 256 + threadIdx.x;   // 512*128 = 65536 threads
    int c = t >> 7, k = t & 127;
    float s = 0.f;
    if (c < 128) {
        for (int m = 0; m < 128; ++m) s += W2[k * 128 + m] * Wg[(128 + m) * 128 + c];
    } else {
        const float* wr = Wih + (size_t)(c - 128) * 128;
        for (int m = 0; m < 128; ++m) s += W2[k * 128 + m] * wr[m];
    }
    WhT[t] = (bf16_t)s;
    if (k == 0) {
        float d = 0.f;
        if (c < 128) { for (int m = 0; m < 128; ++m) d += b2[m] * Wg[(128 + m) * 128 + c]; }
        else { const float* wr = Wih + (size_t)(c - 128) * 128; for (int m = 0; m < 128; ++m) d += b2[m] * wr[m]; }
        db[c] = d;
    }
}

// ---------------- node GEMM: [M,128] (f32 or bf16) @ WT[nd*128][128] bf16 -> bf16 outputs ----------------
// 64-row tile, 512 threads = 8 waves (2 row-groups x 4 col-groups); desc loop in-block.
// Epilogue goes through a padded LDS tile so global stores are 4x256B contiguous segments
// per wave instead of 16x32B row-scattered (store-segment-bound fix).
__global__ __launch_bounds__(512)
void gemm_node(const void* __restrict__ Av, int M, int a_bf16,
               const bf16_t* __restrict__ BT, Descs descs, int nd)
{
    __shared__ bf16_t As[64 * 128];
    __shared__ bf16_t eps[64 * 136];   // +8 bf16 pad per row -> no LDS bank pathology
    const int tid = threadIdx.x;
    const int m0 = blockIdx.x * 64;

    if (!a_bf16) {
        const float* A = (const float*)Av;
#pragma unroll
        for (int st = 0; st < 4; ++st) {
            int f4 = st * 512 + tid;        // float4 index into 64x128 tile
            int row = f4 >> 5;
            int c4 = f4 & 31;
            int grow = m0 + row;
            float4 v = make_float4(0.f, 0.f, 0.f, 0.f);
            if (grow < M) v = *(const float4*)(A + (size_t)grow * 128 + c4 * 4);
            int chunk = c4 >> 1, half = c4 & 1;
            bf16x4 o;
            o[0] = (bf16_t)v.x; o[1] = (bf16_t)v.y; o[2] = (bf16_t)v.z; o[3] = (bf16_t)v.w;
            *(bf16x4*)&As[row * 128 + ((chunk ^ (row & 7)) << 3) + (half << 2)] = o;
        }
    } else {
        const bf16_t* A = (const bf16_t*)Av;
#pragma unroll
        for (int st = 0; st < 2; ++st) {
            int t8 = st * 512 + tid;        // bf16x8 chunk index into 64x128 tile
            int row = t8 >> 4, ch = t8 & 15;
            int grow = m0 + row;
            bf16x8 v = {};
            if (grow < M) v = *(const bf16x8*)(A + (size_t)grow * 128 + ch * 8);
            *(bf16x8*)&As[row * 128 + ((ch ^ (row & 7)) << 3)] = v;
        }
    }
    __syncthreads();

    const int lane = tid & 63;
    const int w = tid >> 6;
    const int wm = w >> 2, wn = w & 3;  // 2 row-groups x 4 col-groups
    const int lm = lane & 15, lk = lane >> 4;

    for (int d = 0; d < nd; ++d) {
        const OutDesc od = descs.d[d];
        const bf16_t* Bt = BT + (size_t)d * (128 * 128);
        f32x4 acc[2][2] = {};
#pragma unroll
        for (int ks = 0; ks < 4; ++ks) {
            bf16x8 afr[2], bfr[2];
#pragma unroll
            for (int nt = 0; nt < 2; ++nt) {
                int n = wn * 32 + nt * 16 + lm;
                bfr[nt] = *(const bf16x8*)(Bt + (size_t)n * 128 + (ks * 4 + lk) * 8);
            }
#pragma unroll
            for (int mt = 0; mt < 2; ++mt) {
                int row = wm * 32 + mt * 16 + lm;
                int ch = ks * 4 + lk;
                afr[mt] = *(const bf16x8*)&As[row * 128 + ((ch ^ (row & 7)) << 3)];
            }
#pragma unroll
            for (int mt = 0; mt < 2; ++mt)
#pragma unroll
                for (int nt = 0; nt < 2; ++nt)
                    acc[mt][nt] = __builtin_amdgcn_mfma_f32_16x16x32_bf16(bfr[nt], afr[mt], acc[mt][nt], 0, 0, 0);
        }
        // epilogue: acc (+bias) -> LDS tile, then coalesced 16B/lane stores
#pragma unroll
        for (int mt = 0; mt < 2; ++mt) {
#pragma unroll
            for (int nt = 0; nt < 2; ++nt) {
                int row = wm * 32 + mt * 16 + lm;
                int n0 = wn * 32 + nt * 16 + lk * 4;
                float4 bv = od.bias ? *(const float4*)(od.bias + n0) : make_float4(0.f, 0.f, 0.f, 0.f);
                bf16x4 o;
                o[0] = (bf16_t)(acc[mt][nt][0] + bv.x);
                o[1] = (bf16_t)(acc[mt][nt][1] + bv.y);
                o[2] = (bf16_t)(acc[mt][nt][2] + bv.z);
                o[3] = (bf16_t)(acc[mt][nt][3] + bv.w);
                *(bf16x4*)&eps[row * 136 + n0] = o;
            }
        }
        __syncthreads();
#pragma unroll
        for (int j = 0; j < 2; ++j) {
            int idx = j * 512 + tid;
            int row = idx >> 4, ch = idx & 15;
            int m = m0 + row;
            if (m < M) {
                bf16x8 v = *(const bf16x8*)&eps[row * 136 + ch * 8];
                *(bf16x8*)(od.ptr + (size_t)m * od.stride + ch * 8) = v;
            }
        }
        __syncthreads();
    }
}

// ---------------- CSR build ----------------
__global__ void hist_deg(const int* __restrict__ ei, int* __restrict__ degi, int E)
{
    int e = blockIdx.x * 256 + threadIdx.x;
    if (e < E) atomicAdd(&degi[ei[E + e]], 1);
}

__global__ __launch_bounds__(512)
void scan_part(const int* __restrict__ degi, int* __restrict__ rowstart,
               int* __restrict__ bsum, int N)
{
    __shared__ int ps[512];
    int t = threadIdx.x;
    int i = blockIdx.x * 512 + t;
    int d = (i < N) ? degi[i] : 0;
    ps[t] = d; __syncthreads();
#pragma unroll
    for (int s = 1; s < 512; s <<= 1) {
        int v = (t >= s) ? ps[t - s] : 0;
        __syncthreads();
        ps[t] += v;
        __syncthreads();
    }
    if (i < N) rowstart[i] = ps[t] - d;
    if (t == 511) bsum[blockIdx.x] = ps[511];
}

__global__ __launch_bounds__(256)
void scan_tops(const int* __restrict__ bsum, int* __restrict__ boff, int nb,
               int* __restrict__ totalOut)
{
    __shared__ int ps[256];
    int t = threadIdx.x;
    int carry = 0;
    for (int base = 0; base < nb; base += 256) {
        int idx = base + t;
        int d = (idx < nb) ? bsum[idx] : 0;
        ps[t] = d; __syncthreads();
#pragma unroll
        for (int s = 1; s < 256; s <<= 1) {
            int v = (t >= s) ? ps[t - s] : 0;
            __syncthreads();
            ps[t] += v;
            __syncthreads();
        }
        if (idx < nb) boff[idx] = carry + ps[t] - d;
        carry += ps[255];
        __syncthreads();
    }
    if (t == 0) *totalOut = carry;
}

__global__ __launch_bounds__(512)
void scan_add(int* __restrict__ rowstart, const int* __restrict__ boff,
              int* __restrict__ cnt, int N)
{
    int i = blockIdx.x * 512 + threadIdx.x;
    if (i < N) { rowstart[i] += boff[blockIdx.x]; cnt[i] = 0; }
}

// pack each edge into dst-sorted slots: {src_as_float, a0..a6} = 2x float4
__global__ void scatter_edges(const int* __restrict__ ei, const float* __restrict__ eattr,
                              const int* __restrict__ rowstart, int* __restrict__ cnt,
                              float4* __restrict__ es, int E)
{
    int e = blockIdx.x * 256 + threadIdx.x;
    if (e >= E) return;
    int src = ei[e], dst = ei[E + e];
    int pos = rowstart[dst] + atomicAdd(&cnt[dst], 1);
    const float* a = eattr + (size_t)e * 7;
    es[(size_t)pos * 2]     = make_float4(__int_as_float(src), a[0], a[1], a[2]);
    es[(size_t)pos * 2 + 1] = make_float4(a[3], a[4], a[5], a[6]);
}

// ---------------- per-node edge aggregation: H[n] = sum_e relu(XA[n]+XB[src]+e@W1c+b1) ----------------
// Proven 2-deep structure; es loads wave-uniform-scalar (readfirstlane'd trip bounds).
__global__ __launch_bounds__(256)
void aggregate(const int* __restrict__ rowstart, const float4* __restrict__ es,
               const bf16_t* __restrict__ XA, const bf16_t* __restrict__ XB,
               const float* __restrict__ W1, const float* __restrict__ b1,
               bf16_t* __restrict__ H, int N)
{
    __shared__ float w1c[7][128];
    __shared__ float b1s[128];
    for (int i = threadIdx.x; i < 7 * 128; i += 256)
        w1c[i >> 7][i & 127] = W1[(256 + (i >> 7)) * 128 + (i & 127)];
    if (threadIdx.x < 128) b1s[threadIdx.x] = b1[threadIdx.x];
    __syncthreads();
    int n = blockIdx.x * 4 + (threadIdx.x >> 6);
    if (n >= N) return;
    int lane = threadIdx.x & 63, c = lane * 2;
    int s = __builtin_amdgcn_readfirstlane(rowstart[n]);
    int e = __builtin_amdgcn_readfirstlane(rowstart[n + 1]);
    bf16x2 xa = *(const bf16x2*)(XA + (size_t)n * 128 + c);
    float base0 = (float)xa[0] + b1s[c], base1 = (float)xa[1] + b1s[c + 1];
    float acc0 = 0.f, acc1 = 0.f;
    int p = s;
    for (; p + 1 < e; p += 2) {
        const float4* q = es + (size_t)p * 2;   // uniform address
        float4 a0 = q[0], a1 = q[1];
        float4 c0 = q[2], c1 = q[3];
        int s0 = __float_as_int(a0.x), s1 = __float_as_int(c0.x);
        bf16x2 xb0 = *(const bf16x2*)(XB + (size_t)s0 * 128 + c);
        bf16x2 xb1 = *(const bf16x2*)(XB + (size_t)s1 * 128 + c);
        float h0 = base0 + (float)xb0[0]
            + a0.y * w1c[0][c] + a0.z * w1c[1][c] + a0.w * w1c[2][c]
            + a1.x * w1c[3][c] + a1.y * w1c[4][c] + a1.z * w1c[5][c] + a1.w * w1c[6][c];
        float h1 = base1 + (float)xb0[1]
            + a0.y * w1c[0][c + 1] + a0.z * w1c[1][c + 1] + a0.w * w1c[2][c + 1]
            + a1.x * w1c[3][c + 1] + a1.y * w1c[4][c + 1] + a1.z * w1c[5][c + 1] + a1.w * w1c[6][c + 1];
        float g0 = base0 + (float)xb1[0]
            + c0.y * w1c[0][c] + c0.z * w1c[1][c] + c0.w * w1c[2][c]
            + c1.x * w1c[3][c] + c1.y * w1c[4][c] + c1.z * w1c[5][c] + c1.w * w1c[6][c];
        float g1 = base1 + (float)xb1[1]
            + c0.y * w1c[0][c + 1] + c0.z * w1c[1][c + 1] + c0.w * w1c[2][c + 1]
            + c1.x * w1c[3][c + 1] + c1.y * w1c[4][c + 1] + c1.z * w1c[5][c + 1] + c1.w * w1c[6][c + 1];
        acc0 += fmaxf(h0, 0.f) + fmaxf(g0, 0.f);
        acc1 += fmaxf(h1, 0.f) + fmaxf(g1, 0.f);
    }
    if (p < e) {
        const float4* q = es + (size_t)p * 2;   // uniform address
        float4 v0 = q[0], v1 = q[1];
        int src = __float_as_int(v0.x);
        bf16x2 xb = *(const bf16x2*)(XB + (size_t)src * 128 + c);
        float h0 = base0 + (float)xb[0]
            + v0.y * w1c[0][c] + v0.z * w1c[1][c] + v0.w * w1c[2][c]
            + v1.x * w1c[3][c] + v1.y * w1c[4][c] + v1.z * w1c[5][c] + v1.w * w1c[6][c];
        float h1 = base1 + (float)xb[1]
            + v0.y * w1c[0][c + 1] + v0.z * w1c[1][c + 1] + v0.w * w1c[2][c + 1]
            + v1.x * w1c[3][c + 1] + v1.y * w1c[4][c + 1] + v1.z * w1c[5][c + 1] + v1.w * w1c[6][c + 1];
        acc0 += fmaxf(h0, 0.f);
        acc1 += fmaxf(h1, 0.f);
    }
    bf16x2 o;
    o[0] = (bf16_t)acc0; o[1] = (bf16_t)acc1;
    *(bf16x2*)(H + (size_t)n * 128 + c) = o;
}

// ---------------- fused gate + GRU + LayerNorm ----------------
__global__ __launch_bounds__(256)
void final_node(const float* __restrict__ x, const bf16_t* __restrict__ GA,
                const bf16_t* __restrict__ GX, const bf16_t* __restrict__ GH,
                const int* __restrict__ rowstart, const float* __restrict__ db,
                const float* __restrict__ bih, const float* __restrict__ gamma,
                const float* __restrict__ beta, float* __restrict__ out, int N)
{
    int n = blockIdx.x * 4 + (threadIdx.x >> 6);
    if (n >= N) return;
    int lane = threadIdx.x & 63, c = lane * 2;
    const bf16_t* ga = GA + (size_t)n * 512;
    bf16x2 vga = *(const bf16x2*)(ga + c);
    bf16x2 vir = *(const bf16x2*)(ga + 128 + c);
    bf16x2 viz = *(const bf16x2*)(ga + 256 + c);
    bf16x2 vin = *(const bf16x2*)(ga + 384 + c);
    bf16x2 vgx = *(const bf16x2*)(GX + (size_t)n * 128 + c);
    const bf16_t* gh = GH + (size_t)n * 384;
    bf16x2 vhr = *(const bf16x2*)(gh + c);
    bf16x2 vhz = *(const bf16x2*)(gh + 128 + c);
    bf16x2 vhn = *(const bf16x2*)(gh + 256 + c);
    float2 xv = *(const float2*)(x + (size_t)n * 128 + c);
    float dg = (float)(rowstart[n + 1] - rowstart[n]);

    float gate0 = sigm((float)vga[0] + (float)vgx[0] + dg * db[c]);
    float gate1 = sigm((float)vga[1] + (float)vgx[1] + dg * db[c + 1]);
    float ir0 = (float)vir[0] + dg * db[128 + c]     + bih[c];
    float ir1 = (float)vir[1] + dg * db[129 + c]     + bih[c + 1];
    float iz0 = (float)viz[0] + dg * db[256 + c]     + bih[128 + c];
    float iz1 = (float)viz[1] + dg * db[257 + c]     + bih[129 + c];
    float in0 = (float)vin[0] + dg * db[384 + c]     + bih[256 + c];
    float in1 = (float)vin[1] + dg * db[385 + c]     + bih[257 + c];
    float r0 = sigm(ir0 + (float)vhr[0]);
    float r1 = sigm(ir1 + (float)vhr[1]);
    float z0 = sigm(iz0 + (float)vhz[0]);
    float z1 = sigm(iz1 + (float)vhz[1]);
    float nn0 = tanhf(in0 + r0 * (float)vhn[0]);
    float nn1 = tanhf(in1 + r1 * (float)vhn[1]);
    float u0 = (1.f - z0) * nn0 + z0 * xv.x;
    float u1 = (1.f - z1) * nn1 + z1 * xv.y;
    float o0 = gate0 * u0 + (1.f - gate0) * xv.x;
    float o1 = gate1 * u1 + (1.f - gate1) * xv.y;

    float s = o0 + o1, q = o0 * o0 + o1 * o1;
    for (int d = 1; d < 64; d <<= 1) { s += __shfl_xor(s, d); q += __shfl_xor(q, d); }
    float mu = s * (1.f / 128.f);
    float var = q * (1.f / 128.f) - mu * mu;
    float inv = rsqrtf(var + 1e-5f);
    float2 ov;
    ov.x = (o0 - mu) * inv * gamma[c] + beta[c];
    ov.y = (o1 - mu) * inv * gamma[c + 1] + beta[c + 1];
    *(float2*)(out + (size_t)n * 128 + c) = ov;
}

extern "C" void kernel_launch(void* const* d_in, const int* in_sizes, int n_in,
                              void* d_out, int out_size, void* d_ws, size_t ws_size,
                              hipStream_t stream)
{
    const float* x     = (const float*)d_in[0];
    const int*   ei    = (const int*)  d_in[1];
    const float* eattr = (const float*)d_in[2];
    const float* W1    = (const float*)d_in[3];
    const float* b1    = (const float*)d_in[4];
    const float* W2    = (const float*)d_in[5];
    const float* b2    = (const float*)d_in[6];
    const float* Wg    = (const float*)d_in[7];
    const float* bg    = (const float*)d_in[8];
    const float* Wih   = (const float*)d_in[9];
    const float* bih   = (const float*)d_in[10];
    const float* Whh   = (const float*)d_in[11];
    const float* bhh   = (const float*)d_in[12];
    const float* gamma = (const float*)d_in[13];
    const float* beta  = (const float*)d_in[14];
    float* out = (float*)d_out;
    const int N = in_sizes[0] / 128;
    const int E = in_sizes[1] / 2;

    char* p = (char*)d_ws;
    auto alloc = [&](size_t b) { char* r = p; p += (b + 255) & ~(size_t)255; return r; };
    bf16_t* WxT   = (bf16_t*)alloc((size_t)768 * 128 * 2);
    bf16_t* WhT   = (bf16_t*)alloc((size_t)512 * 128 * 2);
    float*  db    = (float*) alloc(512 * 4);
    bf16_t* XA    = (bf16_t*)alloc((size_t)N * 128 * 2);
    bf16_t* XB    = (bf16_t*)alloc((size_t)N * 128 * 2);
    bf16_t* GX    = (bf16_t*)alloc((size_t)N * 128 * 2);
    bf16_t* GH    = (bf16_t*)alloc((size_t)N * 384 * 2);
    bf16_t* H     = (bf16_t*)alloc((size_t)N * 128 * 2);
    bf16_t* GA    = (bf16_t*)alloc((size_t)N * 512 * 2);
    int* rowstart = (int*)   alloc((size_t)(N + 1) * 4);
    int* degi     = (int*)   alloc((size_t)N * 4);
    int* cnt      = (int*)   alloc((size_t)N * 4);
    int* bsum     = (int*)   alloc((size_t)(N / 512 + 2) * 4);
    int* boff     = (int*)   alloc((size_t)(N / 512 + 2) * 4);
    float4* es    = (float4*)alloc((size_t)E * 32);

    prep_wx<<<384, 256, 0, stream>>>(W1, Wg, Whh, WxT, degi, N);
    prep_wh<<<256, 256, 0, stream>>>(W2, Wg, Wih, b2, WhT, db);

    Descs dx;
    dx.d[0] = { XA, nullptr, 128 };
    dx.d[1] = { XB, nullptr, 128 };
    dx.d[2] = { GX, bg, 128 };
    dx.d[3] = { GH,       bhh,       384 };
    dx.d[4] = { GH + 128, bhh + 128, 384 };
    dx.d[5] = { GH + 256, bhh + 256, 384 };
    int mt64 = (N + 63) / 64;
    gemm_node<<<mt64, 512, 0, stream>>>(x, N, 0, WxT, dx, 6);

    int nb = (N + 511) / 512;
    hist_deg<<<(E + 255) / 256, 256, 0, stream>>>(ei, degi, E);
    scan_part<<<nb, 512, 0, stream>>>(degi, rowstart, bsum, N);
    scan_tops<<<1, 256, 0, stream>>>(bsum, boff, nb, rowstart + N);
    scan_add<<<nb, 512, 0, stream>>>(rowstart, boff, cnt, N);
    scatter_edges<<<(E + 255) / 256, 256, 0, stream>>>(ei, eattr, rowstart, cnt, es, E);
    aggregate<<<(N + 3) / 4, 256, 0, stream>>>(rowstart, es, XA, XB, W1, b1, H, N);

    Descs dh;
    dh.d[0] = { GA,       nullptr, 512 };
    dh.d[1] = { GA + 128, nullptr, 512 };
    dh.d[2] = { GA + 256, nullptr, 512 };
    dh.d[3] = { GA + 384, nullptr, 512 };
    dh.d[4] = { nullptr, nullptr, 0 };
    dh.d[5] = { nullptr, nullptr, 0 };
    gemm_node<<<mt64, 512, 0, stream>>>(H, N, 1, WhT, dh, 4);

    final_node<<<(N + 3) / 4, 256, 0, stream>>>(x, GA, GX, GH, rowstart, db, bih, gamma, beta, out, N);
}

// Round 16
// 249.578 us; speedup vs baseline: 1.0071x; 1.0071x over previous
//
#include <hip/hip_runtime.h>
#include <hip/hip_bf16.h>

typedef __bf16 bf16_t;
typedef __bf16 bf16x8 __attribute__((ext_vector_type(8)));
typedef __bf16 bf16x4 __attribute__((ext_vector_type(4)));
typedef __bf16 bf16x2 __attribute__((ext_vector_type(2)));
typedef float  f32x4  __attribute__((ext_vector_type(4)));

struct OutDesc { bf16_t* ptr; const float* bias; int stride; };
struct Descs { OutDesc d[6]; };

__device__ __forceinline__ float sigm(float v) { return 1.f / (1.f + __expf(-v)); }

// ---------------- fused weight prep + degree histogram ----------------
// blocks [0,384): WxT   [384,640): WhT+db   [640,...): hist_deg
__global__ __launch_bounds__(256)
void fused_prep(const float* __restrict__ W1, const float* __restrict__ Wg,
                const float* __restrict__ Whh, bf16_t* __restrict__ WxT,
                const float* __restrict__ W2, const float* __restrict__ Wih,
                const float* __restrict__ b2, bf16_t* __restrict__ WhT,
                float* __restrict__ db, const int* __restrict__ ei,
                int* __restrict__ degi, int E)
{
    int bid = blockIdx.x, tid = threadIdx.x;
    if (bid < 384) {
        int t = bid * 256 + tid;   // 768*128
        int c = t >> 7, k = t & 127;
        float v;
        if (c < 128)      v = W1[k * 128 + c];
        else if (c < 256) v = W1[(128 + k) * 128 + (c - 128)];
        else if (c < 384) { int cc = c - 256; v = Wg[k * 128 + cc] + Wg[(256 + k) * 128 + cc]; }
        else              { int j = c - 384; v = Whh[j * 128 + k]; }
        WxT[t] = (bf16_t)v;
    } else if (bid < 640) {
        int t = (bid - 384) * 256 + tid;   // 512*128
        int c = t >> 7, k = t & 127;
        float s = 0.f;
        if (c < 128) {
            for (int m = 0; m < 128; ++m) s += W2[k * 128 + m] * Wg[(128 + m) * 128 + c];
        } else {
            const float* wr = Wih + (size_t)(c - 128) * 128;
            for (int m = 0; m < 128; ++m) s += W2[k * 128 + m] * wr[m];
        }
        WhT[t] = (bf16_t)s;
        if (k == 0) {
            float d = 0.f;
            if (c < 128) { for (int m = 0; m < 128; ++m) d += b2[m] * Wg[(128 + m) * 128 + c]; }
            else { const float* wr = Wih + (size_t)(c - 128) * 128; for (int m = 0; m < 128; ++m) d += b2[m] * wr[m]; }
            db[c] = d;
        }
    } else {
        int e = (bid - 640) * 256 + tid;
        if (e < E) atomicAdd(&degi[ei[E + e]], 1);
    }
}

// ---------------- node GEMM body (R12-proven: 128-row tile, 512 thr, 8 waves 2x4, desc loop) ----------------
__device__ __forceinline__ void gemm_body(bf16_t* __restrict__ As,
    const void* __restrict__ Av, int M, int a_bf16,
    const bf16_t* __restrict__ BT, const Descs& descs, int nd, int blk)
{
    const int tid = threadIdx.x;
    const int m0 = blk * 128;

    if (!a_bf16) {
        const float* A = (const float*)Av;
#pragma unroll
        for (int st = 0; st < 8; ++st) {
            int f4 = st * 512 + tid;
            int row = f4 >> 5;
            int c4 = f4 & 31;
            int grow = m0 + row;
            float4 v = make_float4(0.f, 0.f, 0.f, 0.f);
            if (grow < M) v = *(const float4*)(A + (size_t)grow * 128 + c4 * 4);
            int chunk = c4 >> 1, half = c4 & 1;
            bf16x4 o;
            o[0] = (bf16_t)v.x; o[1] = (bf16_t)v.y; o[2] = (bf16_t)v.z; o[3] = (bf16_t)v.w;
            *(bf16x4*)&As[row * 128 + ((chunk ^ (row & 7)) << 3) + (half << 2)] = o;
        }
    } else {
        const bf16_t* A = (const bf16_t*)Av;
#pragma unroll
        for (int st = 0; st < 4; ++st) {
            int t8 = st * 512 + tid;
            int row = t8 >> 4, ch = t8 & 15;
            int grow = m0 + row;
            bf16x8 v = {};
            if (grow < M) v = *(const bf16x8*)(A + (size_t)grow * 128 + ch * 8);
            *(bf16x8*)&As[row * 128 + ((ch ^ (row & 7)) << 3)] = v;
        }
    }
    __syncthreads();

    const int lane = tid & 63;
    const int w = tid >> 6;
    const int wm = w >> 2, wn = w & 3;
    const int lm = lane & 15, lk = lane >> 4;

    for (int d = 0; d < nd; ++d) {
        const OutDesc od = descs.d[d];
        const bf16_t* Bt = BT + (size_t)d * (128 * 128);
        f32x4 acc[4][2] = {};
#pragma unroll
        for (int ks = 0; ks < 4; ++ks) {
            bf16x8 afr[4], bfr[2];
#pragma unroll
            for (int nt = 0; nt < 2; ++nt) {
                int n = wn * 32 + nt * 16 + lm;
                bfr[nt] = *(const bf16x8*)(Bt + (size_t)n * 128 + (ks * 4 + lk) * 8);
            }
#pragma unroll
            for (int mt = 0; mt < 4; ++mt) {
                int row = wm * 64 + mt * 16 + lm;
                int ch = ks * 4 + lk;
                afr[mt] = *(const bf16x8*)&As[row * 128 + ((ch ^ (row & 7)) << 3)];
            }
#pragma unroll
            for (int mt = 0; mt < 4; ++mt)
#pragma unroll
                for (int nt = 0; nt < 2; ++nt)
                    acc[mt][nt] = __builtin_amdgcn_mfma_f32_16x16x32_bf16(bfr[nt], afr[mt], acc[mt][nt], 0, 0, 0);
        }
#pragma unroll
        for (int mt = 0; mt < 4; ++mt) {
            int m = m0 + wm * 64 + mt * 16 + lm;
            if (m >= M) continue;
#pragma unroll
            for (int nt = 0; nt < 2; ++nt) {
                int n0 = wn * 32 + nt * 16 + lk * 4;
                float4 bv = od.bias ? *(const float4*)(od.bias + n0) : make_float4(0.f, 0.f, 0.f, 0.f);
                bf16x4 o;
                o[0] = (bf16_t)(acc[mt][nt][0] + bv.x);
                o[1] = (bf16_t)(acc[mt][nt][1] + bv.y);
                o[2] = (bf16_t)(acc[mt][nt][2] + bv.z);
                o[3] = (bf16_t)(acc[mt][nt][3] + bv.w);
                *(bf16x4*)(od.ptr + (size_t)m * od.stride + n0) = o;
            }
        }
    }
}

// standalone GEMM (h-pass)
__global__ __launch_bounds__(512)
void gemm_node(const void* __restrict__ Av, int M, int a_bf16,
               const bf16_t* __restrict__ BT, Descs descs, int nd)
{
    __shared__ bf16_t As[128 * 128];
    gemm_body(As, Av, M, a_bf16, BT, descs, nd, blockIdx.x);
}

// ---------------- fused x-pass GEMM + edge scatter (independent work, co-resident) ----------------
// blocks: [0, 2*NG) alternate gemm/scatter; [2*NG, NG+NS) remaining scatter.
__global__ __launch_bounds__(512)
void gemm_scatter(const void* __restrict__ Av, int M, int a_bf16,
                  const bf16_t* __restrict__ BT, Descs descs, int nd, int NG,
                  const int* __restrict__ ei, const float* __restrict__ eattr,
                  const int* __restrict__ rowstart, int* __restrict__ cnt,
                  float4* __restrict__ es, int E)
{
    __shared__ bf16_t As[128 * 128];
    int bid = blockIdx.x;
    int sub; bool isg;
    if (bid < 2 * NG) { isg = (bid & 1) == 0; sub = bid >> 1; }
    else             { isg = false;           sub = bid - NG; }
    if (isg) {
        gemm_body(As, Av, M, a_bf16, BT, descs, nd, sub);
    } else {
        int e = sub * 512 + threadIdx.x;
        if (e >= E) return;
        int src = ei[e], dst = ei[E + e];
        int pos = rowstart[dst] + atomicAdd(&cnt[dst], 1);
        const float* a = eattr + (size_t)e * 7;
        es[(size_t)pos * 2]     = make_float4(__int_as_float(src), a[0], a[1], a[2]);
        es[(size_t)pos * 2 + 1] = make_float4(a[3], a[4], a[5], a[6]);
    }
}

// ---------------- CSR scan ----------------
__global__ __launch_bounds__(512)
void scan_part(const int* __restrict__ degi, int* __restrict__ rowstart,
               int* __restrict__ bsum, int N)
{
    __shared__ int ps[512];
    int t = threadIdx.x;
    int i = blockIdx.x * 512 + t;
    int d = (i < N) ? degi[i] : 0;
    ps[t] = d; __syncthreads();
#pragma unroll
    for (int s = 1; s < 512; s <<= 1) {
        int v = (t >= s) ? ps[t - s] : 0;
        __syncthreads();
        ps[t] += v;
        __syncthreads();
    }
    if (i < N) rowstart[i] = ps[t] - d;
    if (t == 511) bsum[blockIdx.x] = ps[511];
}

__global__ __launch_bounds__(256)
void scan_tops(const int* __restrict__ bsum, int* __restrict__ boff, int nb,
               int* __restrict__ totalOut)
{
    __shared__ int ps[256];
    int t = threadIdx.x;
    int carry = 0;
    for (int base = 0; base < nb; base += 256) {
        int idx = base + t;
        int d = (idx < nb) ? bsum[idx] : 0;
        ps[t] = d; __syncthreads();
#pragma unroll
        for (int s = 1; s < 256; s <<= 1) {
            int v = (t >= s) ? ps[t - s] : 0;
            __syncthreads();
            ps[t] += v;
            __syncthreads();
        }
        if (idx < nb) boff[idx] = carry + ps[t] - d;
        carry += ps[255];
        __syncthreads();
    }
    if (t == 0) *totalOut = carry;
}

__global__ __launch_bounds__(512)
void scan_add(int* __restrict__ rowstart, const int* __restrict__ boff,
              int* __restrict__ cnt, int N)
{
    int i = blockIdx.x * 512 + threadIdx.x;
    if (i < N) { rowstart[i] += boff[blockIdx.x]; cnt[i] = 0; }
}

// ---------------- per-node edge aggregation (R12-proven: scalar-uniform es loads) ----------------
__global__ __launch_bounds__(256)
void aggregate(const int* __restrict__ rowstart, const float4* __restrict__ es,
               const bf16_t* __restrict__ XA, const bf16_t* __restrict__ XB,
               const float* __restrict__ W1, const float* __restrict__ b1,
               bf16_t* __restrict__ H, int N)
{
    __shared__ float w1c[7][128];
    __shared__ float b1s[128];
    for (int i = threadIdx.x; i < 7 * 128; i += 256)
        w1c[i >> 7][i & 127] = W1[(256 + (i >> 7)) * 128 + (i & 127)];
    if (threadIdx.x < 128) b1s[threadIdx.x] = b1[threadIdx.x];
    __syncthreads();
    int n = blockIdx.x * 4 + (threadIdx.x >> 6);
    if (n >= N) return;
    int lane = threadIdx.x & 63, c = lane * 2;
    int s = __builtin_amdgcn_readfirstlane(rowstart[n]);
    int e = __builtin_amdgcn_readfirstlane(rowstart[n + 1]);
    bf16x2 xa = *(const bf16x2*)(XA + (size_t)n * 128 + c);
    float base0 = (float)xa[0] + b1s[c], base1 = (float)xa[1] + b1s[c + 1];
    float acc0 = 0.f, acc1 = 0.f;
    int p = s;
    for (; p + 1 < e; p += 2) {
        const float4* q = es + (size_t)p * 2;
        float4 a0 = q[0], a1 = q[1];
        float4 c0 = q[2], c1 = q[3];
        int s0 = __float_as_int(a0.x), s1 = __float_as_int(c0.x);
        bf16x2 xb0 = *(const bf16x2*)(XB + (size_t)s0 * 128 + c);
        bf16x2 xb1 = *(const bf16x2*)(XB + (size_t)s1 * 128 + c);
        float h0 = base0 + (float)xb0[0]
            + a0.y * w1c[0][c] + a0.z * w1c[1][c] + a0.w * w1c[2][c]
            + a1.x * w1c[3][c] + a1.y * w1c[4][c] + a1.z * w1c[5][c] + a1.w * w1c[6][c];
        float h1 = base1 + (float)xb0[1]
            + a0.y * w1c[0][c + 1] + a0.z * w1c[1][c + 1] + a0.w * w1c[2][c + 1]
            + a1.x * w1c[3][c + 1] + a1.y * w1c[4][c + 1] + a1.z * w1c[5][c + 1] + a1.w * w1c[6][c + 1];
        float g0 = base0 + (float)xb1[0]
            + c0.y * w1c[0][c] + c0.z * w1c[1][c] + c0.w * w1c[2][c]
            + c1.x * w1c[3][c] + c1.y * w1c[4][c] + c1.z * w1c[5][c] + c1.w * w1c[6][c];
        float g1 = base1 + (float)xb1[1]
            + c0.y * w1c[0][c + 1] + c0.z * w1c[1][c + 1] + c0.w * w1c[2][c + 1]
            + c1.x * w1c[3][c + 1] + c1.y * w1c[4][c + 1] + c1.z * w1c[5][c + 1] + c1.w * w1c[6][c + 1];
        acc0 += fmaxf(h0, 0.f) + fmaxf(g0, 0.f);
        acc1 += fmaxf(h1, 0.f) + fmaxf(g1, 0.f);
    }
    if (p < e) {
        const float4* q = es + (size_t)p * 2;
        float4 v0 = q[0], v1 = q[1];
        int src = __float_as_int(v0.x);
        bf16x2 xb = *(const bf16x2*)(XB + (size_t)src * 128 + c);
        float h0 = base0 + (float)xb[0]
            + v0.y * w1c[0][c] + v0.z * w1c[1][c] + v0.w * w1c[2][c]
            + v1.x * w1c[3][c] + v1.y * w1c[4][c] + v1.z * w1c[5][c] + v1.w * w1c[6][c];
        float h1 = base1 + (float)xb[1]
            + v0.y * w1c[0][c + 1] + v0.z * w1c[1][c + 1] + v0.w * w1c[2][c + 1]
            + v1.x * w1c[3][c + 1] + v1.y * w1c[4][c + 1] + v1.z * w1c[5][c + 1] + v1.w * w1c[6][c + 1];
        acc0 += fmaxf(h0, 0.f);
        acc1 += fmaxf(h1, 0.f);
    }
    bf16x2 o;
    o[0] = (bf16_t)acc0; o[1] = (bf16_t)acc1;
    *(bf16x2*)(H + (size_t)n * 128 + c) = o;
}

// ---------------- fused gate + GRU + LayerNorm ----------------
__global__ __launch_bounds__(256)
void final_node(const float* __restrict__ x, const bf16_t* __restrict__ GA,
                const bf16_t* __restrict__ GX, const bf16_t* __restrict__ GH,
                const int* __restrict__ rowstart, const float* __restrict__ db,
                const float* __restrict__ bih, const float* __restrict__ gamma,
                const float* __restrict__ beta, float* __restrict__ out, int N)
{
    int n = blockIdx.x * 4 + (threadIdx.x >> 6);
    if (n >= N) return;
    int lane = threadIdx.x & 63, c = lane * 2;
    const bf16_t* ga = GA + (size_t)n * 512;
    bf16x2 vga = *(const bf16x2*)(ga + c);
    bf16x2 vir = *(const bf16x2*)(ga + 128 + c);
    bf16x2 viz = *(const bf16x2*)(ga + 256 + c);
    bf16x2 vin = *(const bf16x2*)(ga + 384 + c);
    bf16x2 vgx = *(const bf16x2*)(GX + (size_t)n * 128 + c);
    const bf16_t* gh = GH + (size_t)n * 384;
    bf16x2 vhr = *(const bf16x2*)(gh + c);
    bf16x2 vhz = *(const bf16x2*)(gh + 128 + c);
    bf16x2 vhn = *(const bf16x2*)(gh + 256 + c);
    float2 xv = *(const float2*)(x + (size_t)n * 128 + c);
    float dg = (float)(rowstart[n + 1] - rowstart[n]);

    float gate0 = sigm((float)vga[0] + (float)vgx[0] + dg * db[c]);
    float gate1 = sigm((float)vga[1] + (float)vgx[1] + dg * db[c + 1]);
    float ir0 = (float)vir[0] + dg * db[128 + c]     + bih[c];
    float ir1 = (float)vir[1] + dg * db[129 + c]     + bih[c + 1];
    float iz0 = (float)viz[0] + dg * db[256 + c]     + bih[128 + c];
    float iz1 = (float)viz[1] + dg * db[257 + c]     + bih[129 + c];
    float in0 = (float)vin[0] + dg * db[384 + c]     + bih[256 + c];
    float in1 = (float)vin[1] + dg * db[385 + c]     + bih[257 + c];
    float r0 = sigm(ir0 + (float)vhr[0]);
    float r1 = sigm(ir1 + (float)vhr[1]);
    float z0 = sigm(iz0 + (float)vhz[0]);
    float z1 = sigm(iz1 + (float)vhz[1]);
    float nn0 = tanhf(in0 + r0 * (float)vhn[0]);
    float nn1 = tanhf(in1 + r1 * (float)vhn[1]);
    float u0 = (1.f - z0) * nn0 + z0 * xv.x;
    float u1 = (1.f - z1) * nn1 + z1 * xv.y;
    float o0 = gate0 * u0 + (1.f - gate0) * xv.x;
    float o1 = gate1 * u1 + (1.f - gate1) * xv.y;

    float s = o0 + o1, q = o0 * o0 + o1 * o1;
    for (int d = 1; d < 64; d <<= 1) { s += __shfl_xor(s, d); q += __shfl_xor(q, d); }
    float mu = s * (1.f / 128.f);
    float var = q * (1.f / 128.f) - mu * mu;
    float inv = rsqrtf(var + 1e-5f);
    float2 ov;
    ov.x = (o0 - mu) * inv * gamma[c] + beta[c];
    ov.y = (o1 - mu) * inv * gamma[c + 1] + beta[c + 1];
    *(float2*)(out + (size_t)n * 128 + c) = ov;
}

extern "C" void kernel_launch(void* const* d_in, const int* in_sizes, int n_in,
                              void* d_out, int out_size, void* d_ws, size_t ws_size,
                              hipStream_t stream)
{
    const float* x     = (const float*)d_in[0];
    const int*   ei    = (const int*)  d_in[1];
    const float* eattr = (const float*)d_in[2];
    const float* W1    = (const float*)d_in[3];
    const float* b1    = (const float*)d_in[4];
    const float* W2    = (const float*)d_in[5];
    const float* b2    = (const float*)d_in[6];
    const float* Wg    = (const float*)d_in[7];
    const float* bg    = (const float*)d_in[8];
    const float* Wih   = (const float*)d_in[9];
    const float* bih   = (const float*)d_in[10];
    const float* Whh   = (const float*)d_in[11];
    const float* bhh   = (const float*)d_in[12];
    const float* gamma = (const float*)d_in[13];
    const float* beta  = (const float*)d_in[14];
    float* out = (float*)d_out;
    const int N = in_sizes[0] / 128;
    const int E = in_sizes[1] / 2;

    char* p = (char*)d_ws;
    auto alloc = [&](size_t b) { char* r = p; p += (b + 255) & ~(size_t)255; return r; };
    bf16_t* WxT   = (bf16_t*)alloc((size_t)768 * 128 * 2);
    bf16_t* WhT   = (bf16_t*)alloc((size_t)512 * 128 * 2);
    float*  db    = (float*) alloc(512 * 4);
    bf16_t* XA    = (bf16_t*)alloc((size_t)N * 128 * 2);
    bf16_t* XB    = (bf16_t*)alloc((size_t)N * 128 * 2);
    bf16_t* GX    = (bf16_t*)alloc((size_t)N * 128 * 2);
    bf16_t* GH    = (bf16_t*)alloc((size_t)N * 384 * 2);
    bf16_t* H     = (bf16_t*)alloc((size_t)N * 128 * 2);
    bf16_t* GA    = (bf16_t*)alloc((size_t)N * 512 * 2);
    int* rowstart = (int*)   alloc((size_t)(N + 1) * 4);
    int* degi     = (int*)   alloc((size_t)N * 4);
    int* cnt      = (int*)   alloc((size_t)N * 4);
    int* bsum     = (int*)   alloc((size_t)(N / 512 + 2) * 4);
    int* boff     = (int*)   alloc((size_t)(N / 512 + 2) * 4);
    float4* es    = (float4*)alloc((size_t)E * 32);

    hipMemsetAsync(degi, 0, (size_t)N * 4, stream);

    int nhist = (E + 255) / 256;
    fused_prep<<<640 + nhist, 256, 0, stream>>>(W1, Wg, Whh, WxT, W2, Wih, b2, WhT, db,
                                                ei, degi, E);

    int nb = (N + 511) / 512;
    scan_part<<<nb, 512, 0, stream>>>(degi, rowstart, bsum, N);
    scan_tops<<<1, 256, 0, stream>>>(bsum, boff, nb, rowstart + N);
    scan_add<<<nb, 512, 0, stream>>>(rowstart, boff, cnt, N);

    Descs dx;
    dx.d[0] = { XA, nullptr, 128 };
    dx.d[1] = { XB, nullptr, 128 };
    dx.d[2] = { GX, bg, 128 };
    dx.d[3] = { GH,       bhh,       384 };
    dx.d[4] = { GH + 128, bhh + 128, 384 };
    dx.d[5] = { GH + 256, bhh + 256, 384 };
    int NG = (N + 127) / 128;
    int NS = (E + 511) / 512;
    gemm_scatter<<<NG + NS, 512, 0, stream>>>(x, N, 0, WxT, dx, 6, NG,
                                              ei, eattr, rowstart, cnt, es, E);

    aggregate<<<(N + 3) / 4, 256, 0, stream>>>(rowstart, es, XA, XB, W1, b1, H, N);

    Descs dh;
    dh.d[0] = { GA,       nullptr, 512 };
    dh.d[1] = { GA + 128, nullptr, 512 };
    dh.d[2] = { GA + 256, nullptr, 512 };
    dh.d[3] = { GA + 384, nullptr, 512 };
    dh.d[4] = { nullptr, nullptr, 0 };
    dh.d[5] = { nullptr, nullptr, 0 };
    gemm_node<<<NG, 512, 0, stream>>>(H, N, 1, WhT, dh, 4);

    final_node<<<(N + 3) / 4, 256, 0, stream>>>(x, GA, GX, GH, rowstart, db, bih, gamma, beta, out, N);
}

// Round 17
// 239.339 us; speedup vs baseline: 1.0502x; 1.0428x over previous
//
#include <hip/hip_runtime.h>
#include <hip/hip_bf16.h>

typedef __bf16 bf16_t;
typedef __bf16 bf16x8 __attribute__((ext_vector_type(8)));
typedef __bf16 bf16x4 __attribute__((ext_vector_type(4)));
typedef __bf16 bf16x2 __attribute__((ext_vector_type(2)));
typedef float  f32x4  __attribute__((ext_vector_type(4)));

struct OutDesc { bf16_t* ptr; const float* bias; int stride; };
struct Descs { OutDesc d[6]; };

__device__ __forceinline__ float sigm(float v) { return 1.f / (1.f + __expf(-v)); }

// ---------------- fused weight prep + degree histogram ----------------
// blocks [0,384): WxT   [384,640): WhT+db   [640,...): hist_deg
__global__ __launch_bounds__(256)
void fused_prep(const float* __restrict__ W1, const float* __restrict__ Wg,
                const float* __restrict__ Whh, bf16_t* __restrict__ WxT,
                const float* __restrict__ W2, const float* __restrict__ Wih,
                const float* __restrict__ b2, bf16_t* __restrict__ WhT,
                float* __restrict__ db, const int* __restrict__ ei,
                int* __restrict__ degi, int E)
{
    int bid = blockIdx.x, tid = threadIdx.x;
    if (bid < 384) {
        int t = bid * 256 + tid;   // 768*128
        int c = t >> 7, k = t & 127;
        float v;
        if (c < 128)      v = W1[k * 128 + c];
        else if (c < 256) v = W1[(128 + k) * 128 + (c - 128)];
        else if (c < 384) { int cc = c - 256; v = Wg[k * 128 + cc] + Wg[(256 + k) * 128 + cc]; }
        else              { int j = c - 384; v = Whh[j * 128 + k]; }
        WxT[t] = (bf16_t)v;
    } else if (bid < 640) {
        int t = (bid - 384) * 256 + tid;   // 512*128
        int c = t >> 7, k = t & 127;
        float s = 0.f;
        if (c < 128) {
            for (int m = 0; m < 128; ++m) s += W2[k * 128 + m] * Wg[(128 + m) * 128 + c];
        } else {
            const float* wr = Wih + (size_t)(c - 128) * 128;
            for (int m = 0; m < 128; ++m) s += W2[k * 128 + m] * wr[m];
        }
        WhT[t] = (bf16_t)s;
        if (k == 0) {
            float d = 0.f;
            if (c < 128) { for (int m = 0; m < 128; ++m) d += b2[m] * Wg[(128 + m) * 128 + c]; }
            else { const float* wr = Wih + (size_t)(c - 128) * 128; for (int m = 0; m < 128; ++m) d += b2[m] * wr[m]; }
            db[c] = d;
        }
    } else {
        int e = (bid - 640) * 256 + tid;
        if (e < E) atomicAdd(&degi[ei[E + e]], 1);
    }
}

// ---------------- node GEMM: [M,128] (f32 or bf16) @ WT[nd*128][128] bf16 -> bf16 outputs ----------------
// R12-proven: 128-row tile, 512 threads (2x4 waves), in-block desc loop, A staged once.
__global__ __launch_bounds__(512)
void gemm_node(const void* __restrict__ Av, int M, int a_bf16,
               const bf16_t* __restrict__ BT, Descs descs, int nd)
{
    __shared__ bf16_t As[128 * 128];
    const int tid = threadIdx.x;
    const int m0 = blockIdx.x * 128;

    if (!a_bf16) {
        const float* A = (const float*)Av;
#pragma unroll
        for (int st = 0; st < 8; ++st) {
            int f4 = st * 512 + tid;
            int row = f4 >> 5;
            int c4 = f4 & 31;
            int grow = m0 + row;
            float4 v = make_float4(0.f, 0.f, 0.f, 0.f);
            if (grow < M) v = *(const float4*)(A + (size_t)grow * 128 + c4 * 4);
            int chunk = c4 >> 1, half = c4 & 1;
            bf16x4 o;
            o[0] = (bf16_t)v.x; o[1] = (bf16_t)v.y; o[2] = (bf16_t)v.z; o[3] = (bf16_t)v.w;
            *(bf16x4*)&As[row * 128 + ((chunk ^ (row & 7)) << 3) + (half << 2)] = o;
        }
    } else {
        const bf16_t* A = (const bf16_t*)Av;
#pragma unroll
        for (int st = 0; st < 4; ++st) {
            int t8 = st * 512 + tid;
            int row = t8 >> 4, ch = t8 & 15;
            int grow = m0 + row;
            bf16x8 v = {};
            if (grow < M) v = *(const bf16x8*)(A + (size_t)grow * 128 + ch * 8);
            *(bf16x8*)&As[row * 128 + ((ch ^ (row & 7)) << 3)] = v;
        }
    }
    __syncthreads();

    const int lane = tid & 63;
    const int w = tid >> 6;
    const int wm = w >> 2, wn = w & 3;
    const int lm = lane & 15, lk = lane >> 4;

    for (int d = 0; d < nd; ++d) {
        const OutDesc od = descs.d[d];
        const bf16_t* Bt = BT + (size_t)d * (128 * 128);
        f32x4 acc[4][2] = {};
#pragma unroll
        for (int ks = 0; ks < 4; ++ks) {
            bf16x8 afr[4], bfr[2];
#pragma unroll
            for (int nt = 0; nt < 2; ++nt) {
                int n = wn * 32 + nt * 16 + lm;
                bfr[nt] = *(const bf16x8*)(Bt + (size_t)n * 128 + (ks * 4 + lk) * 8);
            }
#pragma unroll
            for (int mt = 0; mt < 4; ++mt) {
                int row = wm * 64 + mt * 16 + lm;
                int ch = ks * 4 + lk;
                afr[mt] = *(const bf16x8*)&As[row * 128 + ((ch ^ (row & 7)) << 3)];
            }
#pragma unroll
            for (int mt = 0; mt < 4; ++mt)
#pragma unroll
                for (int nt = 0; nt < 2; ++nt)
                    acc[mt][nt] = __builtin_amdgcn_mfma_f32_16x16x32_bf16(bfr[nt], afr[mt], acc[mt][nt], 0, 0, 0);
        }
#pragma unroll
        for (int mt = 0; mt < 4; ++mt) {
            int m = m0 + wm * 64 + mt * 16 + lm;
            if (m >= M) continue;
#pragma unroll
            for (int nt = 0; nt < 2; ++nt) {
                int n0 = wn * 32 + nt * 16 + lk * 4;
                float4 bv = od.bias ? *(const float4*)(od.bias + n0) : make_float4(0.f, 0.f, 0.f, 0.f);
                bf16x4 o;
                o[0] = (bf16_t)(acc[mt][nt][0] + bv.x);
                o[1] = (bf16_t)(acc[mt][nt][1] + bv.y);
                o[2] = (bf16_t)(acc[mt][nt][2] + bv.z);
                o[3] = (bf16_t)(acc[mt][nt][3] + bv.w);
                *(bf16x4*)(od.ptr + (size_t)m * od.stride + n0) = o;
            }
        }
    }
}

// ---------------- CSR scan ----------------
__global__ __launch_bounds__(512)
void scan_part(const int* __restrict__ degi, int* __restrict__ rowstart,
               int* __restrict__ bsum, int N)
{
    __shared__ int ps[512];
    int t = threadIdx.x;
    int i = blockIdx.x * 512 + t;
    int d = (i < N) ? degi[i] : 0;
    ps[t] = d; __syncthreads();
#pragma unroll
    for (int s = 1; s < 512; s <<= 1) {
        int v = (t >= s) ? ps[t - s] : 0;
        __syncthreads();
        ps[t] += v;
        __syncthreads();
    }
    if (i < N) rowstart[i] = ps[t] - d;
    if (t == 511) bsum[blockIdx.x] = ps[511];
}

__global__ __launch_bounds__(256)
void scan_tops(const int* __restrict__ bsum, int* __restrict__ boff, int nb,
               int* __restrict__ totalOut)
{
    __shared__ int ps[256];
    int t = threadIdx.x;
    int carry = 0;
    for (int base = 0; base < nb; base += 256) {
        int idx = base + t;
        int d = (idx < nb) ? bsum[idx] : 0;
        ps[t] = d; __syncthreads();
#pragma unroll
        for (int s = 1; s < 256; s <<= 1) {
            int v = (t >= s) ? ps[t - s] : 0;
            __syncthreads();
            ps[t] += v;
            __syncthreads();
        }
        if (idx < nb) boff[idx] = carry + ps[t] - d;
        carry += ps[255];
        __syncthreads();
    }
    if (t == 0) *totalOut = carry;
}

__global__ __launch_bounds__(512)
void scan_add(int* __restrict__ rowstart, const int* __restrict__ boff,
              int* __restrict__ cnt, int N)
{
    int i = blockIdx.x * 512 + threadIdx.x;
    if (i < N) { rowstart[i] += boff[blockIdx.x]; cnt[i] = 0; }
}

// pack each edge into dst-sorted slots: {src_as_float, a0..a6} = 2x float4
__global__ void scatter_edges(const int* __restrict__ ei, const float* __restrict__ eattr,
                              const int* __restrict__ rowstart, int* __restrict__ cnt,
                              float4* __restrict__ es, int E)
{
    int e = blockIdx.x * 256 + threadIdx.x;
    if (e >= E) return;
    int src = ei[e], dst = ei[E + e];
    int pos = rowstart[dst] + atomicAdd(&cnt[dst], 1);
    const float* a = eattr + (size_t)e * 7;
    es[(size_t)pos * 2]     = make_float4(__int_as_float(src), a[0], a[1], a[2]);
    es[(size_t)pos * 2 + 1] = make_float4(a[3], a[4], a[5], a[6]);
}

// ---------------- per-node edge aggregation (R12-proven: scalar-uniform es loads) ----------------
__global__ __launch_bounds__(256)
void aggregate(const int* __restrict__ rowstart, const float4* __restrict__ es,
               const bf16_t* __restrict__ XA, const bf16_t* __restrict__ XB,
               const float* __restrict__ W1, const float* __restrict__ b1,
               bf16_t* __restrict__ H, int N)
{
    __shared__ float w1c[7][128];
    __shared__ float b1s[128];
    for (int i = threadIdx.x; i < 7 * 128; i += 256)
        w1c[i >> 7][i & 127] = W1[(256 + (i >> 7)) * 128 + (i & 127)];
    if (threadIdx.x < 128) b1s[threadIdx.x] = b1[threadIdx.x];
    __syncthreads();
    int n = blockIdx.x * 4 + (threadIdx.x >> 6);
    if (n >= N) return;
    int lane = threadIdx.x & 63, c = lane * 2;
    int s = __builtin_amdgcn_readfirstlane(rowstart[n]);
    int e = __builtin_amdgcn_readfirstlane(rowstart[n + 1]);
    bf16x2 xa = *(const bf16x2*)(XA + (size_t)n * 128 + c);
    float base0 = (float)xa[0] + b1s[c], base1 = (float)xa[1] + b1s[c + 1];
    float acc0 = 0.f, acc1 = 0.f;
    int p = s;
    for (; p + 1 < e; p += 2) {
        const float4* q = es + (size_t)p * 2;
        float4 a0 = q[0], a1 = q[1];
        float4 c0 = q[2], c1 = q[3];
        int s0 = __float_as_int(a0.x), s1 = __float_as_int(c0.x);
        bf16x2 xb0 = *(const bf16x2*)(XB + (size_t)s0 * 128 + c);
        bf16x2 xb1 = *(const bf16x2*)(XB + (size_t)s1 * 128 + c);
        float h0 = base0 + (float)xb0[0]
            + a0.y * w1c[0][c] + a0.z * w1c[1][c] + a0.w * w1c[2][c]
            + a1.x * w1c[3][c] + a1.y * w1c[4][c] + a1.z * w1c[5][c] + a1.w * w1c[6][c];
        float h1 = base1 + (float)xb0[1]
            + a0.y * w1c[0][c + 1] + a0.z * w1c[1][c + 1] + a0.w * w1c[2][c + 1]
            + a1.x * w1c[3][c + 1] + a1.y * w1c[4][c + 1] + a1.z * w1c[5][c + 1] + a1.w * w1c[6][c + 1];
        float g0 = base0 + (float)xb1[0]
            + c0.y * w1c[0][c] + c0.z * w1c[1][c] + c0.w * w1c[2][c]
            + c1.x * w1c[3][c] + c1.y * w1c[4][c] + c1.z * w1c[5][c] + c1.w * w1c[6][c];
        float g1 = base1 + (float)xb1[1]
            + c0.y * w1c[0][c + 1] + c0.z * w1c[1][c + 1] + c0.w * w1c[2][c + 1]
            + c1.x * w1c[3][c + 1] + c1.y * w1c[4][c + 1] + c1.z * w1c[5][c + 1] + c1.w * w1c[6][c + 1];
        acc0 += fmaxf(h0, 0.f) + fmaxf(g0, 0.f);
        acc1 += fmaxf(h1, 0.f) + fmaxf(g1, 0.f);
    }
    if (p < e) {
        const float4* q = es + (size_t)p * 2;
        float4 v0 = q[0], v1 = q[1];
        int src = __float_as_int(v0.x);
        bf16x2 xb = *(const bf16x2*)(XB + (size_t)src * 128 + c);
        float h0 = base0 + (float)xb[0]
            + v0.y * w1c[0][c] + v0.z * w1c[1][c] + v0.w * w1c[2][c]
            + v1.x * w1c[3][c] + v1.y * w1c[4][c] + v1.z * w1c[5][c] + v1.w * w1c[6][c];
        float h1 = base1 + (float)xb[1]
            + v0.y * w1c[0][c + 1] + v0.z * w1c[1][c + 1] + v0.w * w1c[2][c + 1]
            + v1.x * w1c[3][c + 1] + v1.y * w1c[4][c + 1] + v1.z * w1c[5][c + 1] + v1.w * w1c[6][c + 1];
        acc0 += fmaxf(h0, 0.f);
        acc1 += fmaxf(h1, 0.f);
    }
    bf16x2 o;
    o[0] = (bf16_t)acc0; o[1] = (bf16_t)acc1;
    *(bf16x2*)(H + (size_t)n * 128 + c) = o;
}

// ---------------- fused gate + GRU + LayerNorm ----------------
__global__ __launch_bounds__(256)
void final_node(const float* __restrict__ x, const bf16_t* __restrict__ GA,
                const bf16_t* __restrict__ GX, const bf16_t* __restrict__ GH,
                const int* __restrict__ rowstart, const float* __restrict__ db,
                const float* __restrict__ bih, const float* __restrict__ gamma,
                const float* __restrict__ beta, float* __restrict__ out, int N)
{
    int n = blockIdx.x * 4 + (threadIdx.x >> 6);
    if (n >= N) return;
    int lane = threadIdx.x & 63, c = lane * 2;
    const bf16_t* ga = GA + (size_t)n * 512;
    bf16x2 vga = *(const bf16x2*)(ga + c);
    bf16x2 vir = *(const bf16x2*)(ga + 128 + c);
    bf16x2 viz = *(const bf16x2*)(ga + 256 + c);
    bf16x2 vin = *(const bf16x2*)(ga + 384 + c);
    bf16x2 vgx = *(const bf16x2*)(GX + (size_t)n * 128 + c);
    const bf16_t* gh = GH + (size_t)n * 384;
    bf16x2 vhr = *(const bf16x2*)(gh + c);
    bf16x2 vhz = *(const bf16x2*)(gh + 128 + c);
    bf16x2 vhn = *(const bf16x2*)(gh + 256 + c);
    float2 xv = *(const float2*)(x + (size_t)n * 128 + c);
    float dg = (float)(rowstart[n + 1] - rowstart[n]);

    float gate0 = sigm((float)vga[0] + (float)vgx[0] + dg * db[c]);
    float gate1 = sigm((float)vga[1] + (float)vgx[1] + dg * db[c + 1]);
    float ir0 = (float)vir[0] + dg * db[128 + c]     + bih[c];
    float ir1 = (float)vir[1] + dg * db[129 + c]     + bih[c + 1];
    float iz0 = (float)viz[0] + dg * db[256 + c]     + bih[128 + c];
    float iz1 = (float)viz[1] + dg * db[257 + c]     + bih[129 + c];
    float in0 = (float)vin[0] + dg * db[384 + c]     + bih[256 + c];
    float in1 = (float)vin[1] + dg * db[385 + c]     + bih[257 + c];
    float r0 = sigm(ir0 + (float)vhr[0]);
    float r1 = sigm(ir1 + (float)vhr[1]);
    float z0 = sigm(iz0 + (float)vhz[0]);
    float z1 = sigm(iz1 + (float)vhz[1]);
    float nn0 = tanhf(in0 + r0 * (float)vhn[0]);
    float nn1 = tanhf(in1 + r1 * (float)vhn[1]);
    float u0 = (1.f - z0) * nn0 + z0 * xv.x;
    float u1 = (1.f - z1) * nn1 + z1 * xv.y;
    float o0 = gate0 * u0 + (1.f - gate0) * xv.x;
    float o1 = gate1 * u1 + (1.f - gate1) * xv.y;

    float s = o0 + o1, q = o0 * o0 + o1 * o1;
    for (int d = 1; d < 64; d <<= 1) { s += __shfl_xor(s, d); q += __shfl_xor(q, d); }
    float mu = s * (1.f / 128.f);
    float var = q * (1.f / 128.f) - mu * mu;
    float inv = rsqrtf(var + 1e-5f);
    float2 ov;
    ov.x = (o0 - mu) * inv * gamma[c] + beta[c];
    ov.y = (o1 - mu) * inv * gamma[c + 1] + beta[c + 1];
    *(float2*)(out + (size_t)n * 128 + c) = ov;
}

extern "C" void kernel_launch(void* const* d_in, const int* in_sizes, int n_in,
                              void* d_out, int out_size, void* d_ws, size_t ws_size,
                              hipStream_t stream)
{
    const float* x     = (const float*)d_in[0];
    const int*   ei    = (const int*)  d_in[1];
    const float* eattr = (const float*)d_in[2];
    const float* W1    = (const float*)d_in[3];
    const float* b1    = (const float*)d_in[4];
    const float* W2    = (const float*)d_in[5];
    const float* b2    = (const float*)d_in[6];
    const float* Wg    = (const float*)d_in[7];
    const float* bg    = (const float*)d_in[8];
    const float* Wih   = (const float*)d_in[9];
    const float* bih   = (const float*)d_in[10];
    const float* Whh   = (const float*)d_in[11];
    const float* bhh   = (const float*)d_in[12];
    const float* gamma = (const float*)d_in[13];
    const float* beta  = (const float*)d_in[14];
    float* out = (float*)d_out;
    const int N = in_sizes[0] / 128;
    const int E = in_sizes[1] / 2;

    char* p = (char*)d_ws;
    auto alloc = [&](size_t b) { char* r = p; p += (b + 255) & ~(size_t)255; return r; };
    bf16_t* WxT   = (bf16_t*)alloc((size_t)768 * 128 * 2);
    bf16_t* WhT   = (bf16_t*)alloc((size_t)512 * 128 * 2);
    float*  db    = (float*) alloc(512 * 4);
    bf16_t* XA    = (bf16_t*)alloc((size_t)N * 128 * 2);
    bf16_t* XB    = (bf16_t*)alloc((size_t)N * 128 * 2);
    bf16_t* GX    = (bf16_t*)alloc((size_t)N * 128 * 2);
    bf16_t* GH    = (bf16_t*)alloc((size_t)N * 384 * 2);
    bf16_t* H     = (bf16_t*)alloc((size_t)N * 128 * 2);
    bf16_t* GA    = (bf16_t*)alloc((size_t)N * 512 * 2);
    int* rowstart = (int*)   alloc((size_t)(N + 1) * 4);
    int* degi     = (int*)   alloc((size_t)N * 4);
    int* cnt      = (int*)   alloc((size_t)N * 4);
    int* bsum     = (int*)   alloc((size_t)(N / 512 + 2) * 4);
    int* boff     = (int*)   alloc((size_t)(N / 512 + 2) * 4);
    float4* es    = (float4*)alloc((size_t)E * 32);

    hipMemsetAsync(degi, 0, (size_t)N * 4, stream);

    int nhist = (E + 255) / 256;
    fused_prep<<<640 + nhist, 256, 0, stream>>>(W1, Wg, Whh, WxT, W2, Wih, b2, WhT, db,
                                                ei, degi, E);

    Descs dx;
    dx.d[0] = { XA, nullptr, 128 };
    dx.d[1] = { XB, nullptr, 128 };
    dx.d[2] = { GX, bg, 128 };
    dx.d[3] = { GH,       bhh,       384 };
    dx.d[4] = { GH + 128, bhh + 128, 384 };
    dx.d[5] = { GH + 256, bhh + 256, 384 };
    int mt = (N + 127) / 128;
    gemm_node<<<mt, 512, 0, stream>>>(x, N, 0, WxT, dx, 6);

    int nb = (N + 511) / 512;
    scan_part<<<nb, 512, 0, stream>>>(degi, rowstart, bsum, N);
    scan_tops<<<1, 256, 0, stream>>>(bsum, boff, nb, rowstart + N);
    scan_add<<<nb, 512, 0, stream>>>(rowstart, boff, cnt, N);
    scatter_edges<<<(E + 255) / 256, 256, 0, stream>>>(ei, eattr, rowstart, cnt, es, E);
    aggregate<<<(N + 3) / 4, 256, 0, stream>>>(rowstart, es, XA, XB, W1, b1, H, N);

    Descs dh;
    dh.d[0] = { GA,       nullptr, 512 };
    dh.d[1] = { GA + 128, nullptr, 512 };
    dh.d[2] = { GA + 256, nullptr, 512 };
    dh.d[3] = { GA + 384, nullptr, 512 };
    dh.d[4] = { nullptr, nullptr, 0 };
    dh.d[5] = { nullptr, nullptr, 0 };
    gemm_node<<<mt, 512, 0, stream>>>(H, N, 1, WhT, dh, 4);

    final_node<<<(N + 3) / 4, 256, 0, stream>>>(x, GA, GX, GH, rowstart, db, bih, gamma, beta, out, N);
}

// Round 18
// 236.938 us; speedup vs baseline: 1.0608x; 1.0101x over previous
//
#include <hip/hip_runtime.h>
#include <hip/hip_bf16.h>

typedef __bf16 bf16_t;
typedef __bf16 bf16x8 __attribute__((ext_vector_type(8)));
typedef __bf16 bf16x4 __attribute__((ext_vector_type(4)));
typedef __bf16 bf16x2 __attribute__((ext_vector_type(2)));
typedef float  f32x4  __attribute__((ext_vector_type(4)));

struct OutDesc { bf16_t* ptr; const float* bias; int stride; };
struct Descs { OutDesc d[6]; };

__device__ __forceinline__ float sigm(float v) { return 1.f / (1.f + __expf(-v)); }

// ---------------- fused weight prep + degree histogram ----------------
// blocks [0,384): WxT   [384,640): WhT+db   [640,...): hist_deg
__global__ __launch_bounds__(256)
void fused_prep(const float* __restrict__ W1, const float* __restrict__ Wg,
                const float* __restrict__ Whh, bf16_t* __restrict__ WxT,
                const float* __restrict__ W2, const float* __restrict__ Wih,
                const float* __restrict__ b2, bf16_t* __restrict__ WhT,
                float* __restrict__ db, const int* __restrict__ ei,
                int* __restrict__ degi, int E)
{
    int bid = blockIdx.x, tid = threadIdx.x;
    if (bid < 384) {
        int t = bid * 256 + tid;   // 768*128
        int c = t >> 7, k = t & 127;
        float v;
        if (c < 128)      v = W1[k * 128 + c];
        else if (c < 256) v = W1[(128 + k) * 128 + (c - 128)];
        else if (c < 384) { int cc = c - 256; v = Wg[k * 128 + cc] + Wg[(256 + k) * 128 + cc]; }
        else              { int j = c - 384; v = Whh[j * 128 + k]; }
        WxT[t] = (bf16_t)v;
    } else if (bid < 640) {
        int t = (bid - 384) * 256 + tid;   // 512*128
        int c = t >> 7, k = t & 127;
        float s = 0.f;
        if (c < 128) {
            for (int m = 0; m < 128; ++m) s += W2[k * 128 + m] * Wg[(128 + m) * 128 + c];
        } else {
            const float* wr = Wih + (size_t)(c - 128) * 128;
            for (int m = 0; m < 128; ++m) s += W2[k * 128 + m] * wr[m];
        }
        WhT[t] = (bf16_t)s;
        if (k == 0) {
            float d = 0.f;
            if (c < 128) { for (int m = 0; m < 128; ++m) d += b2[m] * Wg[(128 + m) * 128 + c]; }
            else { const float* wr = Wih + (size_t)(c - 128) * 128; for (int m = 0; m < 128; ++m) d += b2[m] * wr[m]; }
            db[c] = d;
        }
    } else {
        int e = (bid - 640) * 256 + tid;
        if (e < E) atomicAdd(&degi[ei[E + e]], 1);
    }
}

// ---------------- node GEMM: [M,128] (f32 or bf16) @ WT[nd*128][128] bf16 -> bf16 outputs ----------------
// 128-row tile, 512 threads (2x4 waves), in-block desc loop. All 8 B-loads per desc hoisted
// ahead of the ks-loop (8 outstanding L2 loads per wave instead of 2 -> MLP fix).
__global__ __launch_bounds__(512)
void gemm_node(const void* __restrict__ Av, int M, int a_bf16,
               const bf16_t* __restrict__ BT, Descs descs, int nd)
{
    __shared__ bf16_t As[128 * 128];
    const int tid = threadIdx.x;
    const int m0 = blockIdx.x * 128;

    if (!a_bf16) {
        const float* A = (const float*)Av;
#pragma unroll
        for (int st = 0; st < 8; ++st) {
            int f4 = st * 512 + tid;
            int row = f4 >> 5;
            int c4 = f4 & 31;
            int grow = m0 + row;
            float4 v = make_float4(0.f, 0.f, 0.f, 0.f);
            if (grow < M) v = *(const float4*)(A + (size_t)grow * 128 + c4 * 4);
            int chunk = c4 >> 1, half = c4 & 1;
            bf16x4 o;
            o[0] = (bf16_t)v.x; o[1] = (bf16_t)v.y; o[2] = (bf16_t)v.z; o[3] = (bf16_t)v.w;
            *(bf16x4*)&As[row * 128 + ((chunk ^ (row & 7)) << 3) + (half << 2)] = o;
        }
    } else {
        const bf16_t* A = (const bf16_t*)Av;
#pragma unroll
        for (int st = 0; st < 4; ++st) {
            int t8 = st * 512 + tid;
            int row = t8 >> 4, ch = t8 & 15;
            int grow = m0 + row;
            bf16x8 v = {};
            if (grow < M) v = *(const bf16x8*)(A + (size_t)grow * 128 + ch * 8);
            *(bf16x8*)&As[row * 128 + ((ch ^ (row & 7)) << 3)] = v;
        }
    }
    __syncthreads();

    const int lane = tid & 63;
    const int w = tid >> 6;
    const int wm = w >> 2, wn = w & 3;
    const int lm = lane & 15, lk = lane >> 4;

    for (int d = 0; d < nd; ++d) {
        const OutDesc od = descs.d[d];
        const bf16_t* Bt = BT + (size_t)d * (128 * 128);
        // hoist ALL B fragments for this desc (8 outstanding loads)
        bf16x8 bfr[4][2];
#pragma unroll
        for (int ks = 0; ks < 4; ++ks)
#pragma unroll
            for (int nt = 0; nt < 2; ++nt) {
                int n = wn * 32 + nt * 16 + lm;
                bfr[ks][nt] = *(const bf16x8*)(Bt + (size_t)n * 128 + (ks * 4 + lk) * 8);
            }
        f32x4 acc[4][2] = {};
#pragma unroll
        for (int ks = 0; ks < 4; ++ks) {
            bf16x8 afr[4];
#pragma unroll
            for (int mt = 0; mt < 4; ++mt) {
                int row = wm * 64 + mt * 16 + lm;
                int ch = ks * 4 + lk;
                afr[mt] = *(const bf16x8*)&As[row * 128 + ((ch ^ (row & 7)) << 3)];
            }
#pragma unroll
            for (int mt = 0; mt < 4; ++mt)
#pragma unroll
                for (int nt = 0; nt < 2; ++nt)
                    acc[mt][nt] = __builtin_amdgcn_mfma_f32_16x16x32_bf16(bfr[ks][nt], afr[mt], acc[mt][nt], 0, 0, 0);
        }
#pragma unroll
        for (int mt = 0; mt < 4; ++mt) {
            int m = m0 + wm * 64 + mt * 16 + lm;
            if (m >= M) continue;
#pragma unroll
            for (int nt = 0; nt < 2; ++nt) {
                int n0 = wn * 32 + nt * 16 + lk * 4;
                float4 bv = od.bias ? *(const float4*)(od.bias + n0) : make_float4(0.f, 0.f, 0.f, 0.f);
                bf16x4 o;
                o[0] = (bf16_t)(acc[mt][nt][0] + bv.x);
                o[1] = (bf16_t)(acc[mt][nt][1] + bv.y);
                o[2] = (bf16_t)(acc[mt][nt][2] + bv.z);
                o[3] = (bf16_t)(acc[mt][nt][3] + bv.w);
                *(bf16x4*)(od.ptr + (size_t)m * od.stride + n0) = o;
            }
        }
    }
}

// ---------------- CSR scan ----------------
__global__ __launch_bounds__(512)
void scan_part(const int* __restrict__ degi, int* __restrict__ rowstart,
               int* __restrict__ bsum, int N)
{
    __shared__ int ps[512];
    int t = threadIdx.x;
    int i = blockIdx.x * 512 + t;
    int d = (i < N) ? degi[i] : 0;
    ps[t] = d; __syncthreads();
#pragma unroll
    for (int s = 1; s < 512; s <<= 1) {
        int v = (t >= s) ? ps[t - s] : 0;
        __syncthreads();
        ps[t] += v;
        __syncthreads();
    }
    if (i < N) rowstart[i] = ps[t] - d;
    if (t == 511) bsum[blockIdx.x] = ps[511];
}

__global__ __launch_bounds__(256)
void scan_tops(const int* __restrict__ bsum, int* __restrict__ boff, int nb,
               int* __restrict__ totalOut)
{
    __shared__ int ps[256];
    int t = threadIdx.x;
    int carry = 0;
    for (int base = 0; base < nb; base += 256) {
        int idx = base + t;
        int d = (idx < nb) ? bsum[idx] : 0;
        ps[t] = d; __syncthreads();
#pragma unroll
        for (int s = 1; s < 256; s <<= 1) {
            int v = (t >= s) ? ps[t - s] : 0;
            __syncthreads();
            ps[t] += v;
            __syncthreads();
        }
        if (idx < nb) boff[idx] = carry + ps[t] - d;
        carry += ps[255];
        __syncthreads();
    }
    if (t == 0) *totalOut = carry;
}

__global__ __launch_bounds__(512)
void scan_add(int* __restrict__ rowstart, const int* __restrict__ boff,
              int* __restrict__ cnt, int N)
{
    int i = blockIdx.x * 512 + threadIdx.x;
    if (i < N) { rowstart[i] += boff[blockIdx.x]; cnt[i] = 0; }
}

// pack each edge into dst-sorted slots: {src_as_float, a0..a6} = 2x float4
__global__ void scatter_edges(const int* __restrict__ ei, const float* __restrict__ eattr,
                              const int* __restrict__ rowstart, int* __restrict__ cnt,
                              float4* __restrict__ es, int E)
{
    int e = blockIdx.x * 256 + threadIdx.x;
    if (e >= E) return;
    int src = ei[e], dst = ei[E + e];
    int pos = rowstart[dst] + atomicAdd(&cnt[dst], 1);
    const float* a = eattr + (size_t)e * 7;
    es[(size_t)pos * 2]     = make_float4(__int_as_float(src), a[0], a[1], a[2]);
    es[(size_t)pos * 2 + 1] = make_float4(a[3], a[4], a[5], a[6]);
}

// ---------------- per-node edge aggregation (R12-proven: scalar-uniform es loads) ----------------
__global__ __launch_bounds__(256)
void aggregate(const int* __restrict__ rowstart, const float4* __restrict__ es,
               const bf16_t* __restrict__ XA, const bf16_t* __restrict__ XB,
               const float* __restrict__ W1, const float* __restrict__ b1,
               bf16_t* __restrict__ H, int N)
{
    __shared__ float w1c[7][128];
    __shared__ float b1s[128];
    for (int i = threadIdx.x; i < 7 * 128; i += 256)
        w1c[i >> 7][i & 127] = W1[(256 + (i >> 7)) * 128 + (i & 127)];
    if (threadIdx.x < 128) b1s[threadIdx.x] = b1[threadIdx.x];
    __syncthreads();
    int n = blockIdx.x * 4 + (threadIdx.x >> 6);
    if (n >= N) return;
    int lane = threadIdx.x & 63, c = lane * 2;
    int s = __builtin_amdgcn_readfirstlane(rowstart[n]);
    int e = __builtin_amdgcn_readfirstlane(rowstart[n + 1]);
    bf16x2 xa = *(const bf16x2*)(XA + (size_t)n * 128 + c);
    float base0 = (float)xa[0] + b1s[c], base1 = (float)xa[1] + b1s[c + 1];
    float acc0 = 0.f, acc1 = 0.f;
    int p = s;
    for (; p + 1 < e; p += 2) {
        const float4* q = es + (size_t)p * 2;
        float4 a0 = q[0], a1 = q[1];
        float4 c0 = q[2], c1 = q[3];
        int s0 = __float_as_int(a0.x), s1 = __float_as_int(c0.x);
        bf16x2 xb0 = *(const bf16x2*)(XB + (size_t)s0 * 128 + c);
        bf16x2 xb1 = *(const bf16x2*)(XB + (size_t)s1 * 128 + c);
        float h0 = base0 + (float)xb0[0]
            + a0.y * w1c[0][c] + a0.z * w1c[1][c] + a0.w * w1c[2][c]
            + a1.x * w1c[3][c] + a1.y * w1c[4][c] + a1.z * w1c[5][c] + a1.w * w1c[6][c];
        float h1 = base1 + (float)xb0[1]
            + a0.y * w1c[0][c + 1] + a0.z * w1c[1][c + 1] + a0.w * w1c[2][c + 1]
            + a1.x * w1c[3][c + 1] + a1.y * w1c[4][c + 1] + a1.z * w1c[5][c + 1] + a1.w * w1c[6][c + 1];
        float g0 = base0 + (float)xb1[0]
            + c0.y * w1c[0][c] + c0.z * w1c[1][c] + c0.w * w1c[2][c]
            + c1.x * w1c[3][c] + c1.y * w1c[4][c] + c1.z * w1c[5][c] + c1.w * w1c[6][c];
        float g1 = base1 + (float)xb1[1]
            + c0.y * w1c[0][c + 1] + c0.z * w1c[1][c + 1] + c0.w * w1c[2][c + 1]
            + c1.x * w1c[3][c + 1] + c1.y * w1c[4][c + 1] + c1.z * w1c[5][c + 1] + c1.w * w1c[6][c + 1];
        acc0 += fmaxf(h0, 0.f) + fmaxf(g0, 0.f);
        acc1 += fmaxf(h1, 0.f) + fmaxf(g1, 0.f);
    }
    if (p < e) {
        const float4* q = es + (size_t)p * 2;
        float4 v0 = q[0], v1 = q[1];
        int src = __float_as_int(v0.x);
        bf16x2 xb = *(const bf16x2*)(XB + (size_t)src * 128 + c);
        float h0 = base0 + (float)xb[0]
            + v0.y * w1c[0][c] + v0.z * w1c[1][c] + v0.w * w1c[2][c]
            + v1.x * w1c[3][c] + v1.y * w1c[4][c] + v1.z * w1c[5][c] + v1.w * w1c[6][c];
        float h1 = base1 + (float)xb[1]
            + v0.y * w1c[0][c + 1] + v0.z * w1c[1][c + 1] + v0.w * w1c[2][c + 1]
            + v1.x * w1c[3][c + 1] + v1.y * w1c[4][c + 1] + v1.z * w1c[5][c + 1] + v1.w * w1c[6][c + 1];
        acc0 += fmaxf(h0, 0.f);
        acc1 += fmaxf(h1, 0.f);
    }
    bf16x2 o;
    o[0] = (bf16_t)acc0; o[1] = (bf16_t)acc1;
    *(bf16x2*)(H + (size_t)n * 128 + c) = o;
}

// ---------------- fused gate + GRU + LayerNorm ----------------
__global__ __launch_bounds__(256)
void final_node(const float* __restrict__ x, const bf16_t* __restrict__ GA,
                const bf16_t* __restrict__ GX, const bf16_t* __restrict__ GH,
                const int* __restrict__ rowstart, const float* __restrict__ db,
                const float* __restrict__ bih, const float* __restrict__ gamma,
                const float* __restrict__ beta, float* __restrict__ out, int N)
{
    int n = blockIdx.x * 4 + (threadIdx.x >> 6);
    if (n >= N) return;
    int lane = threadIdx.x & 63, c = lane * 2;
    const bf16_t* ga = GA + (size_t)n * 512;
    bf16x2 vga = *(const bf16x2*)(ga + c);
    bf16x2 vir = *(const bf16x2*)(ga + 128 + c);
    bf16x2 viz = *(const bf16x2*)(ga + 256 + c);
    bf16x2 vin = *(const bf16x2*)(ga + 384 + c);
    bf16x2 vgx = *(const bf16x2*)(GX + (size_t)n * 128 + c);
    const bf16_t* gh = GH + (size_t)n * 384;
    bf16x2 vhr = *(const bf16x2*)(gh + c);
    bf16x2 vhz = *(const bf16x2*)(gh + 128 + c);
    bf16x2 vhn = *(const bf16x2*)(gh + 256 + c);
    float2 xv = *(const float2*)(x + (size_t)n * 128 + c);
    float dg = (float)(rowstart[n + 1] - rowstart[n]);

    float gate0 = sigm((float)vga[0] + (float)vgx[0] + dg * db[c]);
    float gate1 = sigm((float)vga[1] + (float)vgx[1] + dg * db[c + 1]);
    float ir0 = (float)vir[0] + dg * db[128 + c]     + bih[c];
    float ir1 = (float)vir[1] + dg * db[129 + c]     + bih[c + 1];
    float iz0 = (float)viz[0] + dg * db[256 + c]     + bih[128 + c];
    float iz1 = (float)viz[1] + dg * db[257 + c]     + bih[129 + c];
    float in0 = (float)vin[0] + dg * db[384 + c]     + bih[256 + c];
    float in1 = (float)vin[1] + dg * db[385 + c]     + bih[257 + c];
    float r0 = sigm(ir0 + (float)vhr[0]);
    float r1 = sigm(ir1 + (float)vhr[1]);
    float z0 = sigm(iz0 + (float)vhz[0]);
    float z1 = sigm(iz1 + (float)vhz[1]);
    float nn0 = tanhf(in0 + r0 * (float)vhn[0]);
    float nn1 = tanhf(in1 + r1 * (float)vhn[1]);
    float u0 = (1.f - z0) * nn0 + z0 * xv.x;
    float u1 = (1.f - z1) * nn1 + z1 * xv.y;
    float o0 = gate0 * u0 + (1.f - gate0) * xv.x;
    float o1 = gate1 * u1 + (1.f - gate1) * xv.y;

    float s = o0 + o1, q = o0 * o0 + o1 * o1;
    for (int d = 1; d < 64; d <<= 1) { s += __shfl_xor(s, d); q += __shfl_xor(q, d); }
    float mu = s * (1.f / 128.f);
    float var = q * (1.f / 128.f) - mu * mu;
    float inv = rsqrtf(var + 1e-5f);
    float2 ov;
    ov.x = (o0 - mu) * inv * gamma[c] + beta[c];
    ov.y = (o1 - mu) * inv * gamma[c + 1] + beta[c + 1];
    *(float2*)(out + (size_t)n * 128 + c) = ov;
}

extern "C" void kernel_launch(void* const* d_in, const int* in_sizes, int n_in,
                              void* d_out, int out_size, void* d_ws, size_t ws_size,
                              hipStream_t stream)
{
    const float* x     = (const float*)d_in[0];
    const int*   ei    = (const int*)  d_in[1];
    const float* eattr = (const float*)d_in[2];
    const float* W1    = (const float*)d_in[3];
    const float* b1    = (const float*)d_in[4];
    const float* W2    = (const float*)d_in[5];
    const float* b2    = (const float*)d_in[6];
    const float* Wg    = (const float*)d_in[7];
    const float* bg    = (const float*)d_in[8];
    const float* Wih   = (const float*)d_in[9];
    const float* bih   = (const float*)d_in[10];
    const float* Whh   = (const float*)d_in[11];
    const float* bhh   = (const float*)d_in[12];
    const float* gamma = (const float*)d_in[13];
    const float* beta  = (const float*)d_in[14];
    float* out = (float*)d_out;
    const int N = in_sizes[0] / 128;
    const int E = in_sizes[1] / 2;

    char* p = (char*)d_ws;
    auto alloc = [&](size_t b) { char* r = p; p += (b + 255) & ~(size_t)255; return r; };
    bf16_t* WxT   = (bf16_t*)alloc((size_t)768 * 128 * 2);
    bf16_t* WhT   = (bf16_t*)alloc((size_t)512 * 128 * 2);
    float*  db    = (float*) alloc(512 * 4);
    bf16_t* XA    = (bf16_t*)alloc((size_t)N * 128 * 2);
    bf16_t* XB    = (bf16_t*)alloc((size_t)N * 128 * 2);
    bf16_t* GX    = (bf16_t*)alloc((size_t)N * 128 * 2);
    bf16_t* GH    = (bf16_t*)alloc((size_t)N * 384 * 2);
    bf16_t* H     = (bf16_t*)alloc((size_t)N * 128 * 2);
    bf16_t* GA    = (bf16_t*)alloc((size_t)N * 512 * 2);
    int* rowstart = (int*)   alloc((size_t)(N + 1) * 4);
    int* degi     = (int*)   alloc((size_t)N * 4);
    int* cnt      = (int*)   alloc((size_t)N * 4);
    int* bsum     = (int*)   alloc((size_t)(N / 512 + 2) * 4);
    int* boff     = (int*)   alloc((size_t)(N / 512 + 2) * 4);
    float4* es    = (float4*)alloc((size_t)E * 32);

    hipMemsetAsync(degi, 0, (size_t)N * 4, stream);

    int nhist = (E + 255) / 256;
    fused_prep<<<640 + nhist, 256, 0, stream>>>(W1, Wg, Whh, WxT, W2, Wih, b2, WhT, db,
                                                ei, degi, E);

    Descs dx;
    dx.d[0] = { XA, nullptr, 128 };
    dx.d[1] = { XB, nullptr, 128 };
    dx.d[2] = { GX, bg, 128 };
    dx.d[3] = { GH,       bhh,       384 };
    dx.d[4] = { GH + 128, bhh + 128, 384 };
    dx.d[5] = { GH + 256, bhh + 256, 384 };
    int mt = (N + 127) / 128;
    gemm_node<<<mt, 512, 0, stream>>>(x, N, 0, WxT, dx, 6);

    int nb = (N + 511) / 512;
    scan_part<<<nb, 512, 0, stream>>>(degi, rowstart, bsum, N);
    scan_tops<<<1, 256, 0, stream>>>(bsum, boff, nb, rowstart + N);
    scan_add<<<nb, 512, 0, stream>>>(rowstart, boff, cnt, N);
    scatter_edges<<<(E + 255) / 256, 256, 0, stream>>>(ei, eattr, rowstart, cnt, es, E);
    aggregate<<<(N + 3) / 4, 256, 0, stream>>>(rowstart, es, XA, XB, W1, b1, H, N);

    Descs dh;
    dh.d[0] = { GA,       nullptr, 512 };
    dh.d[1] = { GA + 128, nullptr, 512 };
    dh.d[2] = { GA + 256, nullptr, 512 };
    dh.d[3] = { GA + 384, nullptr, 512 };
    dh.d[4] = { nullptr, nullptr, 0 };
    dh.d[5] = { nullptr, nullptr, 0 };
    gemm_node<<<mt, 512, 0, stream>>>(H, N, 1, WhT, dh, 4);

    final_node<<<(N + 3) / 4, 256, 0, stream>>>(x, GA, GX, GH, rowstart, db, bih, gamma, beta, out, N);
}